// Round 8
// baseline (6541.850 us; speedup 1.0000x reference)
//
#include <hip/hip_runtime.h>
#include <stdint.h>

typedef __bf16 bf16;
typedef bf16 bf16x8 __attribute__((ext_vector_type(8)));
typedef bf16 bf16x4 __attribute__((ext_vector_type(4)));
typedef float f32x4 __attribute__((ext_vector_type(4)));
typedef int i32x4 __attribute__((ext_vector_type(4)));

#define DEV __device__ __forceinline__

// ---------------- workspace layout (bytes) ----------------
// W blobs: per design, fragment blobs of 1KB, order [wave][nt][kt_phys], within blob lane*16B.
// 8-wave layout: d1/d2 8 waves x NT=8 x NKTP=10 = 640 blobs; d3 8 x 4 x 5 = 160.
// (hi/lo K-split REUSES the same physical blobs: phys_kt = kt % NKTP.)
static const size_t OFF_W1 = 0;                                  // 640 blobs * 1024
static const size_t OFF_W2 = OFF_W1 + (size_t)640 * 1024;        // 640 blobs
static const size_t OFF_W3 = OFF_W2 + (size_t)640 * 1024;        // 160 blobs
static const size_t OFF_B1 = OFF_W3 + (size_t)160 * 1024;        // 1024 f32 (orig order)
static const size_t OFF_B2 = OFF_B1 + 4096;
static const size_t OFF_B3 = OFF_B2 + 4096;                      // 512 f32
static const size_t OFF_FEAT = OFF_B3 + 2048;                    // 512*3840 f32
static const size_t WS_NEEDED = OFF_FEAT + (size_t)512 * 3840 * 4;

// EXACT activations (IEEE divide) — r2 showed rcp-based forms drift past the
// absmax threshold through the T=128 recursion.
DEV float sigm(float x) { return 1.f / (1.f + __expf(-x)); }
DEV float tanh_(float x) { return 1.f - 2.f / (__expf(2.f * x) + 1.f); }

// MFMA via inline asm: acc pinned to AGPR ("+a"), weights from VGPR ("v").
// NVA (AGPR weight tuples) retired after r3/r4's instantiation-dependent corruption.
DEV void mfma_bv(f32x4& acc, i32x4 a, i32x4 b) {
  asm("v_mfma_f32_16x16x32_bf16 %0, %1, %2, %0" : "+a"(acc) : "v"(a), "v"(b));
}

// ---------------- prep: pack weights into fragment blobs ----------------
template <int H, int IN, int NT, int NKT>
DEV void packW(const float* __restrict__ Wih, const float* __restrict__ Whh,
               bf16* __restrict__ dst, int i) {
  int e = i & 7, lane = (i >> 3) & 63;
  int rest = i >> 9;
  int kt = rest % NKT; rest /= NKT;
  int nt = rest % NT;  int w = rest / NT;
  int quad = lane >> 4, l16 = lane & 15;
  constexpr int NTG = NT / 4 > 0 ? NT / 4 : 1, UW = NT * 4;
  int unit = w * UW + (nt % NTG) * 16 + l16;
  int g = nt / NTG;
  int r = g * H + unit;
  int k = kt * 32 + quad * 8 + e;
  float v = (k < IN) ? Wih[r * IN + k] : Whh[r * H + (k - IN)];
  dst[i] = (bf16)v;
}

__global__ void prep_kernel(const float* __restrict__ Wih1, const float* __restrict__ Whh1,
                            const float* __restrict__ bih1, const float* __restrict__ bhh1,
                            const float* __restrict__ Wih2, const float* __restrict__ Whh2,
                            const float* __restrict__ bih2, const float* __restrict__ bhh2,
                            const float* __restrict__ Wih3, const float* __restrict__ Whh3,
                            const float* __restrict__ bih3, const float* __restrict__ bhh3,
                            uint8_t* __restrict__ ws) {
  const int gt = blockIdx.x * blockDim.x + threadIdx.x;
  const int gs = gridDim.x * blockDim.x;
  bf16* W1 = (bf16*)(ws + OFF_W1);
  bf16* W2 = (bf16*)(ws + OFF_W2);
  bf16* W3 = (bf16*)(ws + OFF_W3);
  float* B1 = (float*)(ws + OFF_B1);
  float* B2 = (float*)(ws + OFF_B2);
  float* B3 = (float*)(ws + OFF_B3);
  for (int i = gt; i < 640 * 512; i += gs) {
    packW<256, 64, 8, 10>(Wih1, Whh1, W1, i);   // 8 waves x NT=8 x NKTP=10
    packW<256, 64, 8, 10>(Wih2, Whh2, W2, i);
  }
  for (int i = gt; i < 160 * 512; i += gs) packW<128, 32, 4, 5>(Wih3, Whh3, W3, i);  // 8 x 4 x 5
  for (int i = gt; i < 1024; i += gs) { B1[i] = bih1[i] + bhh1[i]; B2[i] = bih2[i] + bhh2[i]; }
  for (int i = gt; i < 512; i += gs) B3[i] = bih3[i] + bhh3[i];
}

// ---------------- persistent LSTM tile, zero inter-block comm ----------------
// Block = 512 thr = 8 waves, 1 block/CU -> 2 waves/SIMD (r5 lesson: the d1 block
// at 1 wave/SIMD is ~50% stall; two waves interleave stream/LDS latency).
//
// hi/lo K-split (r6 lesson): the bf16 quantization of x and recurrent h put the
// worst output element at 2.5 bf16-quanta vs a ~3.2-quanta threshold — any
// recompile rolls +-1 quantum. Logical K = [x_hi | h_hi | x_lo | h_lo] with
// NKT = 2*NKTP; the lo half reuses the SAME physical W blobs (phys = kt-NKTP).
// Gates become ~f32-accurate in inputs; remaining error is W-quant only.
template <int BM, int IN, int H, int T, int NT, int NKT, int NKTP, int NVV, int NS, int DOM>
DEV void lstm_tile3(const float* __restrict__ x0, const float* __restrict__ x1, int halfM,
                    const bf16* __restrict__ Wd, const float* __restrict__ bsum,
                    float* __restrict__ feat, int mg, uint8_t* smem) {
  static_assert(NVV + NS == NT, "split");
  static_assert(NKT == 2 * NKTP, "hi/lo split layout");
  static_assert(NS == 0 || (NKT % 2 == 0), "wrap parity");
  constexpr int MT = BM / 16;
  constexpr int NTG = NT / 4 > 0 ? NT / 4 : 1;
  constexpr int UW = NT * 4;
  constexpr int HALFK = NKTP * 32;   // = IN + H
  constexpr int SROW = NKT * 4 + 1;  // chunks per row (+1 pad -> bank rotate)
  constexpr int AROWE = SROW * 8;
  constexpr int XQ = BM * IN / 4;    // float4 quads of x per timestep
  constexpr int XPT = (XQ + 511) / 512;

  const int tid = threadIdx.x;
  const int lane = tid & 63;
  const int w = tid >> 6;            // 0..7
  const int quad = lane >> 4;
  const int l16 = lane & 15;
  const int rowbase = mg * BM;

  bf16* A = (bf16*)smem;

  const float* xb = (rowbase < halfM) ? x0 : x1;
  const int rowoff = rowbase - ((rowbase < halfM) ? 0 : halfM);

  // zero ALL of A (covers h_hi/h_lo + pads); x regions overwritten by staging below
  for (int i = tid; i < BM * AROWE / 2; i += 512) ((uint32_t*)A)[i] = 0;
  __syncthreads();  // zero visible before x staging (different threads touch same dwords)

  // VGPR-resident W (all NKTP physical kts of resident nt tiles)
  i32x4 wregv[NVV > 0 ? NVV : 1][NKTP];
  {
    const bf16* Wv = Wd + (size_t)(w * NT) * NKTP * 512 + lane * 8;
#pragma unroll
    for (int nt = 0; nt < NVV; ++nt)
#pragma unroll
      for (int kt = 0; kt < NKTP; ++kt)
        wregv[nt][kt] = *(const i32x4*)(Wv + (size_t)(nt * NKTP + kt) * 512);
  }
  const bf16* Wstream = Wd + (size_t)(w * NT + NVV) * NKTP * 512 + lane * 8;

  // biases
  float bias[4][NTG];
#pragma unroll
  for (int g = 0; g < 4; ++g)
#pragma unroll
    for (int ut = 0; ut < NTG; ++ut)
      bias[g][ut] = bsum[g * H + w * UW + ut * 16 + l16];

  i32x4 sbuf[2][NS > 0 ? NS : 1];

  // stage x(0): hi at k, lo residual at k+HALFK
  float4 xr[XPT];
#pragma unroll
  for (int i = 0; i < XPT; ++i) {
    int idx = i * 512 + tid;
    if (idx < XQ) {
      int row = idx / (IN / 4), c4 = idx % (IN / 4);
      xr[i] = *(const float4*)(xb + (size_t)(rowoff + row) * T * IN + c4 * 4);
    }
  }
#pragma unroll
  for (int i = 0; i < XPT; ++i) {
    int idx = i * 512 + tid;
    if (idx < XQ) {
      int row = idx / (IN / 4), c4 = idx % (IN / 4);
      int k = c4 * 4;
      bf16x4 p, q;
      p[0] = (bf16)xr[i].x; q[0] = (bf16)(xr[i].x - (float)p[0]);
      p[1] = (bf16)xr[i].y; q[1] = (bf16)(xr[i].y - (float)p[1]);
      p[2] = (bf16)xr[i].z; q[2] = (bf16)(xr[i].z - (float)p[2]);
      p[3] = (bf16)xr[i].w; q[3] = (bf16)(xr[i].w - (float)p[3]);
      *(bf16x4*)(A + row * AROWE + (k >> 3) * 8 + (k & 7)) = p;
      int kl = k + HALFK;
      *(bf16x4*)(A + row * AROWE + (kl >> 3) * 8 + (kl & 7)) = q;
    }
  }
  __syncthreads();
  if constexpr (NS > 0) {
#pragma unroll
    for (int ns = 0; ns < NS; ++ns)
      sbuf[0][ns] = *(const i32x4*)(Wstream + (size_t)(ns * NKTP) * 512);
  }

  float c[MT * NTG * 4];
#pragma unroll
  for (int i = 0; i < MT * NTG * 4; ++i) c[i] = 0.f;

  f32x4 acc[NT][MT];
#pragma unroll
  for (int nt = 0; nt < NT; ++nt)
#pragma unroll
    for (int mt = 0; mt < MT; ++mt) acc[nt][mt] = f32x4{0.f, 0.f, 0.f, 0.f};

  i32x4 afbuf[2][MT];

#pragma unroll 1
  for (int t = 0; t < T; ++t) {
    // A-fragments for kt=0
#pragma unroll
    for (int mt = 0; mt < MT; ++mt)
      afbuf[0][mt] = *(const i32x4*)(A + (mt * 16 + l16) * AROWE + quad * 8);
    // prefetch x(t+1) (long-latency, overlaps whole K loop)
    if (t < T - 1) {
#pragma unroll
      for (int i = 0; i < XPT; ++i) {
        int idx = i * 512 + tid;
        if (idx < XQ) {
          int row = idx / (IN / 4), c4 = idx % (IN / 4);
          xr[i] = *(const float4*)(xb + (size_t)(rowoff + row) * T * IN +
                                   (size_t)(t + 1) * IN + c4 * 4);
        }
      }
    }
    // K loop over LOGICAL kts; weights indexed by PHYSICAL kt (lo half reuses blobs)
#pragma unroll
    for (int kt = 0; kt < NKT; ++kt) {
      const int ktp = (kt < NKTP) ? kt : kt - NKTP;
      const int ktn = (kt + 1) % NKT;
      const int ktpn = (ktn < NKTP) ? ktn : ktn - NKTP;
      const int pc = kt & 1, pn = (kt + 1) & 1;
      if (kt + 1 < NKT) {
#pragma unroll
        for (int mt = 0; mt < MT; ++mt)
          afbuf[pn][mt] = *(const i32x4*)(A + (mt * 16 + l16) * AROWE + ((kt + 1) * 4 + quad) * 8);
      }
      if constexpr (NS > 0) {
#pragma unroll
        for (int ns = 0; ns < NS; ++ns)
          sbuf[pn][ns] = *(const i32x4*)(Wstream + (size_t)(ns * NKTP + ktpn) * 512);
      }
      // resident first; streamed last (max vmcnt slack, late acc writes)
#pragma unroll
      for (int nt = 0; nt < NVV; ++nt)
#pragma unroll
        for (int mt = 0; mt < MT; ++mt) mfma_bv(acc[nt][mt], afbuf[pc][mt], wregv[nt][ktp]);
      if constexpr (NS > 0) {
#pragma unroll
        for (int ns = 0; ns < NS; ++ns)
#pragma unroll
          for (int mt = 0; mt < MT; ++mt)
            mfma_bv(acc[NVV + ns][mt], afbuf[pc][mt], sbuf[pc][ns]);
      }
    }
    __syncthreads();  // all A(t) reads done; also separates MFMA writes from acc reads
    asm volatile("s_nop 7\n\ts_nop 7\n\ts_nop 7" ::);  // MFMA->v_accvgpr_read hazard pad

    // in-register activation: lane holds i,f,g,o of cell (row=mt*16+quad*4+j,
    // unit=w*UW+ut*16+l16) at acc[g*NTG+ut][mt][j]
#pragma unroll
    for (int mt = 0; mt < MT; ++mt)
#pragma unroll
      for (int ut = 0; ut < NTG; ++ut)
#pragma unroll
        for (int j = 0; j < 4; ++j) {
          float gi = acc[0 * NTG + ut][mt][j] + bias[0][ut];
          float gf = acc[1 * NTG + ut][mt][j] + bias[1][ut];
          float gg = acc[2 * NTG + ut][mt][j] + bias[2][ut];
          float go = acc[3 * NTG + ut][mt][j] + bias[3][ut];
          int ci = (mt * NTG + ut) * 4 + j;
          float cc = sigm(gf) * c[ci] + sigm(gi) * tanh_(gg);
          c[ci] = cc;
          float hv = sigm(go) * tanh_(cc);
          int row = mt * 16 + quad * 4 + j;
          if (t < T - 1) {
            int kg = IN + w * UW + ut * 16 + l16;
            bf16 hb = (bf16)hv;
            A[row * AROWE + (kg >> 3) * 8 + (kg & 7)] = hb;
            int kl = kg + HALFK;  // h_lo residual
            A[row * AROWE + (kl >> 3) * 8 + (kl & 7)] = (bf16)(hv - (float)hb);
          } else {
            int R = rowbase + row;
            int unit = w * UW + ut * 16 + l16;
            int b, col;
            if (DOM == 0) {
              if (R < 512) { b = R; col = unit; }
              else         { b = R - 512; col = 256 + unit; }
            } else if (DOM == 1) {
              b = R; col = 512 + unit;
            } else {
              int rr = R; int base = 768;
              if (rr >= 6144) { rr -= 6144; base = 2304; }
              b = rr / 12; int p = rr - b * 12;
              col = base + p * 128 + unit;
            }
            feat[(size_t)b * 3840 + col] = hv;
          }
        }
    // re-zero acc for next step HERE (VALU writes stay before the barrier ->
    // safe distance from next step's first MFMA srcC read)
#pragma unroll
    for (int nt = 0; nt < NT; ++nt)
#pragma unroll
      for (int mt = 0; mt < MT; ++mt) acc[nt][mt] = f32x4{0.f, 0.f, 0.f, 0.f};
    // write x(t+1): hi + lo residual
    if (t < T - 1) {
#pragma unroll
      for (int i = 0; i < XPT; ++i) {
        int idx = i * 512 + tid;
        if (idx < XQ) {
          int row = idx / (IN / 4), c4 = idx % (IN / 4);
          int k = c4 * 4;
          bf16x4 p, q;
          p[0] = (bf16)xr[i].x; q[0] = (bf16)(xr[i].x - (float)p[0]);
          p[1] = (bf16)xr[i].y; q[1] = (bf16)(xr[i].y - (float)p[1]);
          p[2] = (bf16)xr[i].z; q[2] = (bf16)(xr[i].z - (float)p[2]);
          p[3] = (bf16)xr[i].w; q[3] = (bf16)(xr[i].w - (float)p[3]);
          *(bf16x4*)(A + row * AROWE + (k >> 3) * 8 + (k & 7)) = p;
          int kl = k + HALFK;
          *(bf16x4*)(A + row * AROWE + (kl >> 3) * 8 + (kl & 7)) = q;
        }
      }
    }
    __syncthreads();
  }
}

__global__ __launch_bounds__(512, 2) void lstm_main(const float* __restrict__ gh,
                                                    const float* __restrict__ ga,
                                                    const float* __restrict__ gv,
                                                    const float* __restrict__ ph,
                                                    const float* __restrict__ pa,
                                                    uint8_t* __restrict__ ws) {
  extern __shared__ uint8_t smem[];
  float* feat = (float*)(ws + OFF_FEAT);
  int bid = blockIdx.x;
  if (bid < 64) {
    lstm_tile3<16, 64, 256, 128, 8, 20, 10, 2, 6, 0>(
        gh, ga, 512, (const bf16*)(ws + OFF_W1), (const float*)(ws + OFF_B1), feat, bid, smem);
  } else if (bid < 96) {
    lstm_tile3<16, 64, 256, 128, 8, 20, 10, 2, 6, 1>(
        gv, gv, 512, (const bf16*)(ws + OFF_W2), (const float*)(ws + OFF_B2), feat, bid - 64, smem);
  } else {
    // design-3: BM=32, all W VGPR-resident (NS=0)
    lstm_tile3<32, 32, 128, 64, 4, 10, 5, 4, 0, 2>(
        ph, pa, 6144, (const bf16*)(ws + OFF_W3), (const float*)(ws + OFF_B3), feat, bid - 96, smem);
  }
}

// ---------------- final FC ----------------
__global__ void fc_kernel(const float* __restrict__ feat, const float* __restrict__ cg,
                          const float* __restrict__ Wfc, const float* __restrict__ bfc,
                          float* __restrict__ out) {
  int b = blockIdx.x, tid = threadIdx.x;
  float a0 = 0.f, a1 = 0.f;
  for (int c = tid; c < 3840; c += 256) {
    float f = feat[(size_t)b * 3840 + c];
    a0 += f * Wfc[c];
    a1 += f * Wfc[3872 + c];
  }
  if (tid < 32) {
    float f = cg[b * 32 + tid];
    a0 += f * Wfc[3840 + tid];
    a1 += f * Wfc[3872 + 3840 + tid];
  }
#pragma unroll
  for (int o = 32; o > 0; o >>= 1) {
    a0 += __shfl_down(a0, o);
    a1 += __shfl_down(a1, o);
  }
  __shared__ float red[8];
  int wv = tid >> 6;
  if ((tid & 63) == 0) { red[wv * 2] = a0; red[wv * 2 + 1] = a1; }
  __syncthreads();
  if (tid == 0) {
    out[b * 2 + 0] = red[0] + red[2] + red[4] + red[6] + bfc[0];
    out[b * 2 + 1] = red[1] + red[3] + red[5] + red[7] + bfc[1];
  }
}

extern "C" void kernel_launch(void* const* d_in, const int* in_sizes, int n_in, void* d_out,
                              int out_size, void* d_ws, size_t ws_size, hipStream_t stream) {
  const float* cg = (const float*)d_in[0];
  const float* gh = (const float*)d_in[1];
  const float* ga = (const float*)d_in[2];
  const float* gv = (const float*)d_in[3];
  const float* ph = (const float*)d_in[4];
  const float* pa = (const float*)d_in[5];
  const float* Wih1 = (const float*)d_in[6];
  const float* Whh1 = (const float*)d_in[7];
  const float* bih1 = (const float*)d_in[8];
  const float* bhh1 = (const float*)d_in[9];
  const float* Wih2 = (const float*)d_in[10];
  const float* Whh2 = (const float*)d_in[11];
  const float* bih2 = (const float*)d_in[12];
  const float* bhh2 = (const float*)d_in[13];
  const float* Wih3 = (const float*)d_in[14];
  const float* Whh3 = (const float*)d_in[15];
  const float* bih3 = (const float*)d_in[16];
  const float* bhh3 = (const float*)d_in[17];
  const float* Wfc = (const float*)d_in[18];
  const float* bfc = (const float*)d_in[19];
  uint8_t* ws = (uint8_t*)d_ws;
  if (ws_size < WS_NEEDED) return;

  hipLaunchKernelGGL(prep_kernel, dim3(512), dim3(256), 0, stream, Wih1, Whh1, bih1, bhh1,
                     Wih2, Whh2, bih2, bhh2, Wih3, Whh3, bih3, bhh3, ws);

  // LDS: A only. d1/d2: 16*(81*8)*2 = 20736 B; d3: 32*(41*8)*2 = 20992 B. <64KB default.
  hipLaunchKernelGGL(lstm_main, dim3(480), dim3(512), 20992, stream, gh, ga, gv, ph, pa, ws);

  hipLaunchKernelGGL(fc_kernel, dim3(512), dim3(256), 0, stream,
                     (const float*)(ws + OFF_FEAT), cg, Wfc, bfc, (float*)d_out);
}

// Round 9
// 5588.533 us; speedup vs baseline: 1.1706x; 1.1706x over previous
//
#include <hip/hip_runtime.h>
#include <stdint.h>

typedef __bf16 bf16;
typedef bf16 bf16x8 __attribute__((ext_vector_type(8)));
typedef bf16 bf16x4 __attribute__((ext_vector_type(4)));
typedef float f32x4 __attribute__((ext_vector_type(4)));
typedef int i32x4 __attribute__((ext_vector_type(4)));

#define DEV __device__ __forceinline__

// ---------------- workspace layout (bytes) ----------------
// W blobs: per design, fragment blobs of 1KB, order [wave][nt][kt_phys], within blob lane*16B.
// 8-wave layout: d1/d2 8 waves x NT=8 x NKTP=10 = 640 blobs; d3 8 x 4 x 5 = 160.
// (hi/lo K-split REUSES the same physical blobs: phys_kt = kt % NKTP.)
static const size_t OFF_W1 = 0;                                  // 640 blobs * 1024
static const size_t OFF_W2 = OFF_W1 + (size_t)640 * 1024;        // 640 blobs
static const size_t OFF_W3 = OFF_W2 + (size_t)640 * 1024;        // 160 blobs
static const size_t OFF_B1 = OFF_W3 + (size_t)160 * 1024;        // 1024 f32 (orig order)
static const size_t OFF_B2 = OFF_B1 + 4096;
static const size_t OFF_B3 = OFF_B2 + 4096;                      // 512 f32
static const size_t OFF_FEAT = OFF_B3 + 2048;                    // 512*3840 f32
static const size_t WS_NEEDED = OFF_FEAT + (size_t)512 * 3840 * 4;

// EXACT activations (IEEE divide) — r2 showed rcp-based forms drift past the
// absmax threshold through the T=128 recursion.
DEV float sigm(float x) { return 1.f / (1.f + __expf(-x)); }
DEV float tanh_(float x) { return 1.f - 2.f / (__expf(2.f * x) + 1.f); }

// MFMA with accumulator in ARCH VGPR ("+v"), legal on gfx950's unified file.
// r8 lesson: "+a" acc under __launch_bounds__(512,2) made the allocator split
// the 256-reg budget 128 VGPR / 128 AGPR; the ~190-VGPR working set spilled
// ~60 regs -> 4.5 GB/1.6 GB scratch traffic and 3.5x slowdown. With zero AGPRs
// the full 256 regs are arch VGPRs and everything fits.
DEV void mfma_vv(f32x4& acc, i32x4 a, i32x4 b) {
  asm("v_mfma_f32_16x16x32_bf16 %0, %1, %2, %0" : "+v"(acc) : "v"(a), "v"(b));
}

// ---------------- prep: pack weights into fragment blobs ----------------
template <int H, int IN, int NT, int NKT>
DEV void packW(const float* __restrict__ Wih, const float* __restrict__ Whh,
               bf16* __restrict__ dst, int i) {
  int e = i & 7, lane = (i >> 3) & 63;
  int rest = i >> 9;
  int kt = rest % NKT; rest /= NKT;
  int nt = rest % NT;  int w = rest / NT;
  int quad = lane >> 4, l16 = lane & 15;
  constexpr int NTG = NT / 4 > 0 ? NT / 4 : 1, UW = NT * 4;
  int unit = w * UW + (nt % NTG) * 16 + l16;
  int g = nt / NTG;
  int r = g * H + unit;
  int k = kt * 32 + quad * 8 + e;
  float v = (k < IN) ? Wih[r * IN + k] : Whh[r * H + (k - IN)];
  dst[i] = (bf16)v;
}

__global__ void prep_kernel(const float* __restrict__ Wih1, const float* __restrict__ Whh1,
                            const float* __restrict__ bih1, const float* __restrict__ bhh1,
                            const float* __restrict__ Wih2, const float* __restrict__ Whh2,
                            const float* __restrict__ bih2, const float* __restrict__ bhh2,
                            const float* __restrict__ Wih3, const float* __restrict__ Whh3,
                            const float* __restrict__ bih3, const float* __restrict__ bhh3,
                            uint8_t* __restrict__ ws) {
  const int gt = blockIdx.x * blockDim.x + threadIdx.x;
  const int gs = gridDim.x * blockDim.x;
  bf16* W1 = (bf16*)(ws + OFF_W1);
  bf16* W2 = (bf16*)(ws + OFF_W2);
  bf16* W3 = (bf16*)(ws + OFF_W3);
  float* B1 = (float*)(ws + OFF_B1);
  float* B2 = (float*)(ws + OFF_B2);
  float* B3 = (float*)(ws + OFF_B3);
  for (int i = gt; i < 640 * 512; i += gs) {
    packW<256, 64, 8, 10>(Wih1, Whh1, W1, i);   // 8 waves x NT=8 x NKTP=10
    packW<256, 64, 8, 10>(Wih2, Whh2, W2, i);
  }
  for (int i = gt; i < 160 * 512; i += gs) packW<128, 32, 4, 5>(Wih3, Whh3, W3, i);  // 8 x 4 x 5
  for (int i = gt; i < 1024; i += gs) { B1[i] = bih1[i] + bhh1[i]; B2[i] = bih2[i] + bhh2[i]; }
  for (int i = gt; i < 512; i += gs) B3[i] = bih3[i] + bhh3[i];
}

// ---------------- persistent LSTM tile, zero inter-block comm ----------------
// Block = 512 thr = 8 waves, 1 block/CU -> 2 waves/SIMD (r5 lesson: the d1 block
// at 1 wave/SIMD is ~50% stall; two waves interleave stream/LDS latency).
//
// hi/lo K-split (r6/r8 lesson, VERIFIED r8: absmax 0.0195 -> 0.0078): logical
// K = [x_hi | h_hi | x_lo | h_lo], NKT = 2*NKTP, lo half reuses the SAME
// physical W blobs. Gates ~f32-accurate in inputs; error is W-quant only.
template <int BM, int IN, int H, int T, int NT, int NKT, int NKTP, int NVV, int NS, int DOM>
DEV void lstm_tile3(const float* __restrict__ x0, const float* __restrict__ x1, int halfM,
                    const bf16* __restrict__ Wd, const float* __restrict__ bsum,
                    float* __restrict__ feat, int mg, uint8_t* smem) {
  static_assert(NVV + NS == NT, "split");
  static_assert(NKT == 2 * NKTP, "hi/lo split layout");
  static_assert(NS == 0 || (NKT % 2 == 0), "wrap parity");
  constexpr int MT = BM / 16;
  constexpr int NTG = NT / 4 > 0 ? NT / 4 : 1;
  constexpr int UW = NT * 4;
  constexpr int HALFK = NKTP * 32;   // = IN + H
  constexpr int SROW = NKT * 4 + 1;  // chunks per row (+1 pad -> bank rotate)
  constexpr int AROWE = SROW * 8;
  constexpr int XQ = BM * IN / 4;    // float4 quads of x per timestep
  constexpr int XPT = (XQ + 511) / 512;

  const int tid = threadIdx.x;
  const int lane = tid & 63;
  const int w = tid >> 6;            // 0..7
  const int quad = lane >> 4;
  const int l16 = lane & 15;
  const int rowbase = mg * BM;

  bf16* A = (bf16*)smem;

  const float* xb = (rowbase < halfM) ? x0 : x1;
  const int rowoff = rowbase - ((rowbase < halfM) ? 0 : halfM);

  // zero ALL of A (covers h_hi/h_lo + pads); x regions overwritten by staging below
  for (int i = tid; i < BM * AROWE / 2; i += 512) ((uint32_t*)A)[i] = 0;
  __syncthreads();  // zero visible before x staging (different threads touch same dwords)

  // VGPR-resident W (all NKTP physical kts of resident nt tiles)
  i32x4 wregv[NVV > 0 ? NVV : 1][NKTP];
  {
    const bf16* Wv = Wd + (size_t)(w * NT) * NKTP * 512 + lane * 8;
#pragma unroll
    for (int nt = 0; nt < NVV; ++nt)
#pragma unroll
      for (int kt = 0; kt < NKTP; ++kt)
        wregv[nt][kt] = *(const i32x4*)(Wv + (size_t)(nt * NKTP + kt) * 512);
  }
  const bf16* Wstream = Wd + (size_t)(w * NT + NVV) * NKTP * 512 + lane * 8;

  // biases
  float bias[4][NTG];
#pragma unroll
  for (int g = 0; g < 4; ++g)
#pragma unroll
    for (int ut = 0; ut < NTG; ++ut)
      bias[g][ut] = bsum[g * H + w * UW + ut * 16 + l16];

  i32x4 sbuf[2][NS > 0 ? NS : 1];

  // stage x(0): hi at k, lo residual at k+HALFK
  float4 xr[XPT];
#pragma unroll
  for (int i = 0; i < XPT; ++i) {
    int idx = i * 512 + tid;
    if (idx < XQ) {
      int row = idx / (IN / 4), c4 = idx % (IN / 4);
      xr[i] = *(const float4*)(xb + (size_t)(rowoff + row) * T * IN + c4 * 4);
    }
  }
#pragma unroll
  for (int i = 0; i < XPT; ++i) {
    int idx = i * 512 + tid;
    if (idx < XQ) {
      int row = idx / (IN / 4), c4 = idx % (IN / 4);
      int k = c4 * 4;
      bf16x4 p, q;
      p[0] = (bf16)xr[i].x; q[0] = (bf16)(xr[i].x - (float)p[0]);
      p[1] = (bf16)xr[i].y; q[1] = (bf16)(xr[i].y - (float)p[1]);
      p[2] = (bf16)xr[i].z; q[2] = (bf16)(xr[i].z - (float)p[2]);
      p[3] = (bf16)xr[i].w; q[3] = (bf16)(xr[i].w - (float)p[3]);
      *(bf16x4*)(A + row * AROWE + (k >> 3) * 8 + (k & 7)) = p;
      int kl = k + HALFK;
      *(bf16x4*)(A + row * AROWE + (kl >> 3) * 8 + (kl & 7)) = q;
    }
  }
  __syncthreads();
  if constexpr (NS > 0) {
#pragma unroll
    for (int ns = 0; ns < NS; ++ns)
      sbuf[0][ns] = *(const i32x4*)(Wstream + (size_t)(ns * NKTP) * 512);
  }

  float c[MT * NTG * 4];
#pragma unroll
  for (int i = 0; i < MT * NTG * 4; ++i) c[i] = 0.f;

  f32x4 acc[NT][MT];
#pragma unroll
  for (int nt = 0; nt < NT; ++nt)
#pragma unroll
    for (int mt = 0; mt < MT; ++mt) acc[nt][mt] = f32x4{0.f, 0.f, 0.f, 0.f};

  i32x4 afbuf[2][MT];

#pragma unroll 1
  for (int t = 0; t < T; ++t) {
    // A-fragments for kt=0
#pragma unroll
    for (int mt = 0; mt < MT; ++mt)
      afbuf[0][mt] = *(const i32x4*)(A + (mt * 16 + l16) * AROWE + quad * 8);
    // prefetch x(t+1) (long-latency, overlaps whole K loop)
    if (t < T - 1) {
#pragma unroll
      for (int i = 0; i < XPT; ++i) {
        int idx = i * 512 + tid;
        if (idx < XQ) {
          int row = idx / (IN / 4), c4 = idx % (IN / 4);
          xr[i] = *(const float4*)(xb + (size_t)(rowoff + row) * T * IN +
                                   (size_t)(t + 1) * IN + c4 * 4);
        }
      }
    }
    // K loop over LOGICAL kts; weights indexed by PHYSICAL kt (lo half reuses blobs)
#pragma unroll
    for (int kt = 0; kt < NKT; ++kt) {
      const int ktp = (kt < NKTP) ? kt : kt - NKTP;
      const int ktn = (kt + 1) % NKT;
      const int ktpn = (ktn < NKTP) ? ktn : ktn - NKTP;
      const int pc = kt & 1, pn = (kt + 1) & 1;
      if (kt + 1 < NKT) {
#pragma unroll
        for (int mt = 0; mt < MT; ++mt)
          afbuf[pn][mt] = *(const i32x4*)(A + (mt * 16 + l16) * AROWE + ((kt + 1) * 4 + quad) * 8);
      }
      if constexpr (NS > 0) {
#pragma unroll
        for (int ns = 0; ns < NS; ++ns)
          sbuf[pn][ns] = *(const i32x4*)(Wstream + (size_t)(ns * NKTP + ktpn) * 512);
      }
      // resident first; streamed last (max vmcnt slack, late acc writes)
#pragma unroll
      for (int nt = 0; nt < NVV; ++nt)
#pragma unroll
        for (int mt = 0; mt < MT; ++mt) mfma_vv(acc[nt][mt], afbuf[pc][mt], wregv[nt][ktp]);
      if constexpr (NS > 0) {
#pragma unroll
        for (int ns = 0; ns < NS; ++ns)
#pragma unroll
          for (int mt = 0; mt < MT; ++mt)
            mfma_vv(acc[NVV + ns][mt], afbuf[pc][mt], sbuf[pc][ns]);
      }
    }
    __syncthreads();  // all A(t) reads done; also separates MFMA writes from acc reads
    asm volatile("s_nop 7\n\ts_nop 7\n\ts_nop 7" ::);  // MFMA->VALU-read hazard pad

    // in-register activation: lane holds i,f,g,o of cell (row=mt*16+quad*4+j,
    // unit=w*UW+ut*16+l16) at acc[g*NTG+ut][mt][j]
#pragma unroll
    for (int mt = 0; mt < MT; ++mt)
#pragma unroll
      for (int ut = 0; ut < NTG; ++ut)
#pragma unroll
        for (int j = 0; j < 4; ++j) {
          float gi = acc[0 * NTG + ut][mt][j] + bias[0][ut];
          float gf = acc[1 * NTG + ut][mt][j] + bias[1][ut];
          float gg = acc[2 * NTG + ut][mt][j] + bias[2][ut];
          float go = acc[3 * NTG + ut][mt][j] + bias[3][ut];
          int ci = (mt * NTG + ut) * 4 + j;
          float cc = sigm(gf) * c[ci] + sigm(gi) * tanh_(gg);
          c[ci] = cc;
          float hv = sigm(go) * tanh_(cc);
          int row = mt * 16 + quad * 4 + j;
          if (t < T - 1) {
            int kg = IN + w * UW + ut * 16 + l16;
            bf16 hb = (bf16)hv;
            A[row * AROWE + (kg >> 3) * 8 + (kg & 7)] = hb;
            int kl = kg + HALFK;  // h_lo residual
            A[row * AROWE + (kl >> 3) * 8 + (kl & 7)] = (bf16)(hv - (float)hb);
          } else {
            int R = rowbase + row;
            int unit = w * UW + ut * 16 + l16;
            int b, col;
            if (DOM == 0) {
              if (R < 512) { b = R; col = unit; }
              else         { b = R - 512; col = 256 + unit; }
            } else if (DOM == 1) {
              b = R; col = 512 + unit;
            } else {
              int rr = R; int base = 768;
              if (rr >= 6144) { rr -= 6144; base = 2304; }
              b = rr / 12; int p = rr - b * 12;
              col = base + p * 128 + unit;
            }
            feat[(size_t)b * 3840 + col] = hv;
          }
        }
    // re-zero acc for next step HERE (VALU writes stay before the barrier ->
    // safe distance from next step's first MFMA srcC read)
#pragma unroll
    for (int nt = 0; nt < NT; ++nt)
#pragma unroll
      for (int mt = 0; mt < MT; ++mt) acc[nt][mt] = f32x4{0.f, 0.f, 0.f, 0.f};
    // write x(t+1): hi + lo residual
    if (t < T - 1) {
#pragma unroll
      for (int i = 0; i < XPT; ++i) {
        int idx = i * 512 + tid;
        if (idx < XQ) {
          int row = idx / (IN / 4), c4 = idx % (IN / 4);
          int k = c4 * 4;
          bf16x4 p, q;
          p[0] = (bf16)xr[i].x; q[0] = (bf16)(xr[i].x - (float)p[0]);
          p[1] = (bf16)xr[i].y; q[1] = (bf16)(xr[i].y - (float)p[1]);
          p[2] = (bf16)xr[i].z; q[2] = (bf16)(xr[i].z - (float)p[2]);
          p[3] = (bf16)xr[i].w; q[3] = (bf16)(xr[i].w - (float)p[3]);
          *(bf16x4*)(A + row * AROWE + (k >> 3) * 8 + (k & 7)) = p;
          int kl = k + HALFK;
          *(bf16x4*)(A + row * AROWE + (kl >> 3) * 8 + (kl & 7)) = q;
        }
      }
    }
    __syncthreads();
  }
}

__global__ __launch_bounds__(512, 2) void lstm_main(const float* __restrict__ gh,
                                                    const float* __restrict__ ga,
                                                    const float* __restrict__ gv,
                                                    const float* __restrict__ ph,
                                                    const float* __restrict__ pa,
                                                    uint8_t* __restrict__ ws) {
  extern __shared__ uint8_t smem[];
  float* feat = (float*)(ws + OFF_FEAT);
  int bid = blockIdx.x;
  if (bid < 64) {
    lstm_tile3<16, 64, 256, 128, 8, 20, 10, 2, 6, 0>(
        gh, ga, 512, (const bf16*)(ws + OFF_W1), (const float*)(ws + OFF_B1), feat, bid, smem);
  } else if (bid < 96) {
    lstm_tile3<16, 64, 256, 128, 8, 20, 10, 2, 6, 1>(
        gv, gv, 512, (const bf16*)(ws + OFF_W2), (const float*)(ws + OFF_B2), feat, bid - 64, smem);
  } else {
    // design-3: BM=32, all W VGPR-resident (NS=0)
    lstm_tile3<32, 32, 128, 64, 4, 10, 5, 4, 0, 2>(
        ph, pa, 6144, (const bf16*)(ws + OFF_W3), (const float*)(ws + OFF_B3), feat, bid - 96, smem);
  }
}

// ---------------- final FC ----------------
__global__ void fc_kernel(const float* __restrict__ feat, const float* __restrict__ cg,
                          const float* __restrict__ Wfc, const float* __restrict__ bfc,
                          float* __restrict__ out) {
  int b = blockIdx.x, tid = threadIdx.x;
  float a0 = 0.f, a1 = 0.f;
  for (int c = tid; c < 3840; c += 256) {
    float f = feat[(size_t)b * 3840 + c];
    a0 += f * Wfc[c];
    a1 += f * Wfc[3872 + c];
  }
  if (tid < 32) {
    float f = cg[b * 32 + tid];
    a0 += f * Wfc[3840 + tid];
    a1 += f * Wfc[3872 + 3840 + tid];
  }
#pragma unroll
  for (int o = 32; o > 0; o >>= 1) {
    a0 += __shfl_down(a0, o);
    a1 += __shfl_down(a1, o);
  }
  __shared__ float red[8];
  int wv = tid >> 6;
  if ((tid & 63) == 0) { red[wv * 2] = a0; red[wv * 2 + 1] = a1; }
  __syncthreads();
  if (tid == 0) {
    out[b * 2 + 0] = red[0] + red[2] + red[4] + red[6] + bfc[0];
    out[b * 2 + 1] = red[1] + red[3] + red[5] + red[7] + bfc[1];
  }
}

extern "C" void kernel_launch(void* const* d_in, const int* in_sizes, int n_in, void* d_out,
                              int out_size, void* d_ws, size_t ws_size, hipStream_t stream) {
  const float* cg = (const float*)d_in[0];
  const float* gh = (const float*)d_in[1];
  const float* ga = (const float*)d_in[2];
  const float* gv = (const float*)d_in[3];
  const float* ph = (const float*)d_in[4];
  const float* pa = (const float*)d_in[5];
  const float* Wih1 = (const float*)d_in[6];
  const float* Whh1 = (const float*)d_in[7];
  const float* bih1 = (const float*)d_in[8];
  const float* bhh1 = (const float*)d_in[9];
  const float* Wih2 = (const float*)d_in[10];
  const float* Whh2 = (const float*)d_in[11];
  const float* bih2 = (const float*)d_in[12];
  const float* bhh2 = (const float*)d_in[13];
  const float* Wih3 = (const float*)d_in[14];
  const float* Whh3 = (const float*)d_in[15];
  const float* bih3 = (const float*)d_in[16];
  const float* bhh3 = (const float*)d_in[17];
  const float* Wfc = (const float*)d_in[18];
  const float* bfc = (const float*)d_in[19];
  uint8_t* ws = (uint8_t*)d_ws;
  if (ws_size < WS_NEEDED) return;

  hipLaunchKernelGGL(prep_kernel, dim3(512), dim3(256), 0, stream, Wih1, Whh1, bih1, bhh1,
                     Wih2, Whh2, bih2, bhh2, Wih3, Whh3, bih3, bhh3, ws);

  // LDS: A only. d1/d2: 16*(81*8)*2 = 20736 B; d3: 32*(41*8)*2 = 20992 B. <64KB default.
  hipLaunchKernelGGL(lstm_main, dim3(480), dim3(512), 20992, stream, gh, ga, gv, ph, pa, ws);

  hipLaunchKernelGGL(fc_kernel, dim3(512), dim3(256), 0, stream,
                     (const float*)(ws + OFF_FEAT), cg, Wfc, bfc, (float*)d_out);
}

// Round 10
// 4762.286 us; speedup vs baseline: 1.3737x; 1.1735x over previous
//
#include <hip/hip_runtime.h>
#include <stdint.h>

typedef __bf16 bf16;
typedef bf16 bf16x8 __attribute__((ext_vector_type(8)));
typedef bf16 bf16x4 __attribute__((ext_vector_type(4)));
typedef float f32x4 __attribute__((ext_vector_type(4)));
typedef int i32x4 __attribute__((ext_vector_type(4)));
typedef short i16x8 __attribute__((ext_vector_type(8)));

#define DEV __device__ __forceinline__

// ---------------- workspace layout (bytes) ----------------
// W blobs: per design, fragment blobs of 1KB, order [wave][nt][kt_phys], within blob lane*16B.
// 8-wave layout: d1/d2 8 waves x NT=8 x NKTP=10 = 640 blobs; d3 8 x 4 x 5 = 160.
// (hi/lo K-split REUSES the same physical blobs: phys_kt = kt % NKTP.)
static const size_t OFF_W1 = 0;                                  // 640 blobs * 1024
static const size_t OFF_W2 = OFF_W1 + (size_t)640 * 1024;        // 640 blobs
static const size_t OFF_W3 = OFF_W2 + (size_t)640 * 1024;        // 160 blobs
static const size_t OFF_B1 = OFF_W3 + (size_t)160 * 1024;        // 1024 f32 (orig order)
static const size_t OFF_B2 = OFF_B1 + 4096;
static const size_t OFF_B3 = OFF_B2 + 4096;                      // 512 f32
static const size_t OFF_FEAT = OFF_B3 + 2048;                    // 512*3840 f32
static const size_t WS_NEEDED = OFF_FEAT + (size_t)512 * 3840 * 4;

// EXACT activations (IEEE divide) — r2 showed rcp-based forms drift past the
// absmax threshold through the T=128 recursion.
DEV float sigm(float x) { return 1.f / (1.f + __expf(-x)); }
DEV float tanh_(float x) { return 1.f - 2.f / (__expf(2.f * x) + 1.f); }

// MFMA via COMPILER INTRINSIC, not inline asm. r8/r9 lesson: any inline asm in
// the kernel makes the backend assume it may touch AGPRs; on gfx950's unified
// register file that reserves HALF the per-wave budget as AGPRs (VGPR_Count
// was pinned at 128 under __launch_bounds__(512,2)), spilling the ~208-VGPR
// working set to scratch (4.4 GB FETCH). The intrinsic lets the attributor
// prove no-AGPR -> full 256 arch VGPRs, and the compiler handles MFMA hazards.
DEV void mfma_vv(f32x4& acc, i32x4 a, i32x4 b) {
  acc = __builtin_amdgcn_mfma_f32_16x16x32_bf16(
      __builtin_bit_cast(i16x8, a), __builtin_bit_cast(i16x8, b), acc, 0, 0, 0);
}

// ---------------- prep: pack weights into fragment blobs ----------------
template <int H, int IN, int NT, int NKT>
DEV void packW(const float* __restrict__ Wih, const float* __restrict__ Whh,
               bf16* __restrict__ dst, int i) {
  int e = i & 7, lane = (i >> 3) & 63;
  int rest = i >> 9;
  int kt = rest % NKT; rest /= NKT;
  int nt = rest % NT;  int w = rest / NT;
  int quad = lane >> 4, l16 = lane & 15;
  constexpr int NTG = NT / 4 > 0 ? NT / 4 : 1, UW = NT * 4;
  int unit = w * UW + (nt % NTG) * 16 + l16;
  int g = nt / NTG;
  int r = g * H + unit;
  int k = kt * 32 + quad * 8 + e;
  float v = (k < IN) ? Wih[r * IN + k] : Whh[r * H + (k - IN)];
  dst[i] = (bf16)v;
}

__global__ void prep_kernel(const float* __restrict__ Wih1, const float* __restrict__ Whh1,
                            const float* __restrict__ bih1, const float* __restrict__ bhh1,
                            const float* __restrict__ Wih2, const float* __restrict__ Whh2,
                            const float* __restrict__ bih2, const float* __restrict__ bhh2,
                            const float* __restrict__ Wih3, const float* __restrict__ Whh3,
                            const float* __restrict__ bih3, const float* __restrict__ bhh3,
                            uint8_t* __restrict__ ws) {
  const int gt = blockIdx.x * blockDim.x + threadIdx.x;
  const int gs = gridDim.x * blockDim.x;
  bf16* W1 = (bf16*)(ws + OFF_W1);
  bf16* W2 = (bf16*)(ws + OFF_W2);
  bf16* W3 = (bf16*)(ws + OFF_W3);
  float* B1 = (float*)(ws + OFF_B1);
  float* B2 = (float*)(ws + OFF_B2);
  float* B3 = (float*)(ws + OFF_B3);
  for (int i = gt; i < 640 * 512; i += gs) {
    packW<256, 64, 8, 10>(Wih1, Whh1, W1, i);   // 8 waves x NT=8 x NKTP=10
    packW<256, 64, 8, 10>(Wih2, Whh2, W2, i);
  }
  for (int i = gt; i < 160 * 512; i += gs) packW<128, 32, 4, 5>(Wih3, Whh3, W3, i);  // 8 x 4 x 5
  for (int i = gt; i < 1024; i += gs) { B1[i] = bih1[i] + bhh1[i]; B2[i] = bih2[i] + bhh2[i]; }
  for (int i = gt; i < 512; i += gs) B3[i] = bih3[i] + bhh3[i];
}

// ---------------- persistent LSTM tile, zero inter-block comm ----------------
// Block = 512 thr = 8 waves, 1 block/CU -> 2 waves/SIMD (r5 lesson: the d1 block
// at 1 wave/SIMD is ~50% stall; two waves interleave stream/LDS latency).
//
// hi/lo K-split (r6/r8 lesson, VERIFIED r8: absmax 0.0195 -> 0.0078): logical
// K = [x_hi | h_hi | x_lo | h_lo], NKT = 2*NKTP, lo half reuses the SAME
// physical W blobs. Gates ~f32-accurate in inputs; error is W-quant only.
template <int BM, int IN, int H, int T, int NT, int NKT, int NKTP, int NVV, int NS, int DOM>
DEV void lstm_tile3(const float* __restrict__ x0, const float* __restrict__ x1, int halfM,
                    const bf16* __restrict__ Wd, const float* __restrict__ bsum,
                    float* __restrict__ feat, int mg, uint8_t* smem) {
  static_assert(NVV + NS == NT, "split");
  static_assert(NKT == 2 * NKTP, "hi/lo split layout");
  static_assert(NS == 0 || (NKT % 2 == 0), "wrap parity");
  constexpr int MT = BM / 16;
  constexpr int NTG = NT / 4 > 0 ? NT / 4 : 1;
  constexpr int UW = NT * 4;
  constexpr int HALFK = NKTP * 32;   // = IN + H
  constexpr int SROW = NKT * 4 + 1;  // chunks per row (+1 pad -> bank rotate)
  constexpr int AROWE = SROW * 8;
  constexpr int XQ = BM * IN / 4;    // float4 quads of x per timestep
  constexpr int XPT = (XQ + 511) / 512;

  const int tid = threadIdx.x;
  const int lane = tid & 63;
  const int w = tid >> 6;            // 0..7
  const int quad = lane >> 4;
  const int l16 = lane & 15;
  const int rowbase = mg * BM;

  bf16* A = (bf16*)smem;

  const float* xb = (rowbase < halfM) ? x0 : x1;
  const int rowoff = rowbase - ((rowbase < halfM) ? 0 : halfM);

  // zero ALL of A (covers h_hi/h_lo + pads); x regions overwritten by staging below
  for (int i = tid; i < BM * AROWE / 2; i += 512) ((uint32_t*)A)[i] = 0;
  __syncthreads();  // zero visible before x staging (different threads touch same dwords)

  // VGPR-resident W (all NKTP physical kts of resident nt tiles)
  i32x4 wregv[NVV > 0 ? NVV : 1][NKTP];
  {
    const bf16* Wv = Wd + (size_t)(w * NT) * NKTP * 512 + lane * 8;
#pragma unroll
    for (int nt = 0; nt < NVV; ++nt)
#pragma unroll
      for (int kt = 0; kt < NKTP; ++kt)
        wregv[nt][kt] = *(const i32x4*)(Wv + (size_t)(nt * NKTP + kt) * 512);
  }
  const bf16* Wstream = Wd + (size_t)(w * NT + NVV) * NKTP * 512 + lane * 8;

  // biases
  float bias[4][NTG];
#pragma unroll
  for (int g = 0; g < 4; ++g)
#pragma unroll
    for (int ut = 0; ut < NTG; ++ut)
      bias[g][ut] = bsum[g * H + w * UW + ut * 16 + l16];

  i32x4 sbuf[2][NS > 0 ? NS : 1];

  // stage x(0): hi at k, lo residual at k+HALFK
  float4 xr[XPT];
#pragma unroll
  for (int i = 0; i < XPT; ++i) {
    int idx = i * 512 + tid;
    if (idx < XQ) {
      int row = idx / (IN / 4), c4 = idx % (IN / 4);
      xr[i] = *(const float4*)(xb + (size_t)(rowoff + row) * T * IN + c4 * 4);
    }
  }
#pragma unroll
  for (int i = 0; i < XPT; ++i) {
    int idx = i * 512 + tid;
    if (idx < XQ) {
      int row = idx / (IN / 4), c4 = idx % (IN / 4);
      int k = c4 * 4;
      bf16x4 p, q;
      p[0] = (bf16)xr[i].x; q[0] = (bf16)(xr[i].x - (float)p[0]);
      p[1] = (bf16)xr[i].y; q[1] = (bf16)(xr[i].y - (float)p[1]);
      p[2] = (bf16)xr[i].z; q[2] = (bf16)(xr[i].z - (float)p[2]);
      p[3] = (bf16)xr[i].w; q[3] = (bf16)(xr[i].w - (float)p[3]);
      *(bf16x4*)(A + row * AROWE + (k >> 3) * 8 + (k & 7)) = p;
      int kl = k + HALFK;
      *(bf16x4*)(A + row * AROWE + (kl >> 3) * 8 + (kl & 7)) = q;
    }
  }
  __syncthreads();
  if constexpr (NS > 0) {
#pragma unroll
    for (int ns = 0; ns < NS; ++ns)
      sbuf[0][ns] = *(const i32x4*)(Wstream + (size_t)(ns * NKTP) * 512);
  }

  float c[MT * NTG * 4];
#pragma unroll
  for (int i = 0; i < MT * NTG * 4; ++i) c[i] = 0.f;

  f32x4 acc[NT][MT];
#pragma unroll
  for (int nt = 0; nt < NT; ++nt)
#pragma unroll
    for (int mt = 0; mt < MT; ++mt) acc[nt][mt] = f32x4{0.f, 0.f, 0.f, 0.f};

  i32x4 afbuf[2][MT];

#pragma unroll 1
  for (int t = 0; t < T; ++t) {
    // A-fragments for kt=0
#pragma unroll
    for (int mt = 0; mt < MT; ++mt)
      afbuf[0][mt] = *(const i32x4*)(A + (mt * 16 + l16) * AROWE + quad * 8);
    // prefetch x(t+1) (long-latency, overlaps whole K loop)
    if (t < T - 1) {
#pragma unroll
      for (int i = 0; i < XPT; ++i) {
        int idx = i * 512 + tid;
        if (idx < XQ) {
          int row = idx / (IN / 4), c4 = idx % (IN / 4);
          xr[i] = *(const float4*)(xb + (size_t)(rowoff + row) * T * IN +
                                   (size_t)(t + 1) * IN + c4 * 4);
        }
      }
    }
    // K loop over LOGICAL kts; weights indexed by PHYSICAL kt (lo half reuses blobs)
#pragma unroll
    for (int kt = 0; kt < NKT; ++kt) {
      const int ktp = (kt < NKTP) ? kt : kt - NKTP;
      const int ktn = (kt + 1) % NKT;
      const int ktpn = (ktn < NKTP) ? ktn : ktn - NKTP;
      const int pc = kt & 1, pn = (kt + 1) & 1;
      if (kt + 1 < NKT) {
#pragma unroll
        for (int mt = 0; mt < MT; ++mt)
          afbuf[pn][mt] = *(const i32x4*)(A + (mt * 16 + l16) * AROWE + ((kt + 1) * 4 + quad) * 8);
      }
      if constexpr (NS > 0) {
#pragma unroll
        for (int ns = 0; ns < NS; ++ns)
          sbuf[pn][ns] = *(const i32x4*)(Wstream + (size_t)(ns * NKTP + ktpn) * 512);
      }
      // resident first; streamed last (max vmcnt slack, late acc writes)
#pragma unroll
      for (int nt = 0; nt < NVV; ++nt)
#pragma unroll
        for (int mt = 0; mt < MT; ++mt) mfma_vv(acc[nt][mt], afbuf[pc][mt], wregv[nt][ktp]);
      if constexpr (NS > 0) {
#pragma unroll
        for (int ns = 0; ns < NS; ++ns)
#pragma unroll
          for (int mt = 0; mt < MT; ++mt)
            mfma_vv(acc[NVV + ns][mt], afbuf[pc][mt], sbuf[pc][ns]);
      }
    }
    __syncthreads();  // all A(t) reads done before h-writes below

    // in-register activation: lane holds i,f,g,o of cell (row=mt*16+quad*4+j,
    // unit=w*UW+ut*16+l16) at acc[g*NTG+ut][mt][j]
#pragma unroll
    for (int mt = 0; mt < MT; ++mt)
#pragma unroll
      for (int ut = 0; ut < NTG; ++ut)
#pragma unroll
        for (int j = 0; j < 4; ++j) {
          float gi = acc[0 * NTG + ut][mt][j] + bias[0][ut];
          float gf = acc[1 * NTG + ut][mt][j] + bias[1][ut];
          float gg = acc[2 * NTG + ut][mt][j] + bias[2][ut];
          float go = acc[3 * NTG + ut][mt][j] + bias[3][ut];
          int ci = (mt * NTG + ut) * 4 + j;
          float cc = sigm(gf) * c[ci] + sigm(gi) * tanh_(gg);
          c[ci] = cc;
          float hv = sigm(go) * tanh_(cc);
          int row = mt * 16 + quad * 4 + j;
          if (t < T - 1) {
            int kg = IN + w * UW + ut * 16 + l16;
            bf16 hb = (bf16)hv;
            A[row * AROWE + (kg >> 3) * 8 + (kg & 7)] = hb;
            int kl = kg + HALFK;  // h_lo residual
            A[row * AROWE + (kl >> 3) * 8 + (kl & 7)] = (bf16)(hv - (float)hb);
          } else {
            int R = rowbase + row;
            int unit = w * UW + ut * 16 + l16;
            int b, col;
            if (DOM == 0) {
              if (R < 512) { b = R; col = unit; }
              else         { b = R - 512; col = 256 + unit; }
            } else if (DOM == 1) {
              b = R; col = 512 + unit;
            } else {
              int rr = R; int base = 768;
              if (rr >= 6144) { rr -= 6144; base = 2304; }
              b = rr / 12; int p = rr - b * 12;
              col = base + p * 128 + unit;
            }
            feat[(size_t)b * 3840 + col] = hv;
          }
        }
    // re-zero acc for next step
#pragma unroll
    for (int nt = 0; nt < NT; ++nt)
#pragma unroll
      for (int mt = 0; mt < MT; ++mt) acc[nt][mt] = f32x4{0.f, 0.f, 0.f, 0.f};
    // write x(t+1): hi + lo residual
    if (t < T - 1) {
#pragma unroll
      for (int i = 0; i < XPT; ++i) {
        int idx = i * 512 + tid;
        if (idx < XQ) {
          int row = idx / (IN / 4), c4 = idx % (IN / 4);
          int k = c4 * 4;
          bf16x4 p, q;
          p[0] = (bf16)xr[i].x; q[0] = (bf16)(xr[i].x - (float)p[0]);
          p[1] = (bf16)xr[i].y; q[1] = (bf16)(xr[i].y - (float)p[1]);
          p[2] = (bf16)xr[i].z; q[2] = (bf16)(xr[i].z - (float)p[2]);
          p[3] = (bf16)xr[i].w; q[3] = (bf16)(xr[i].w - (float)p[3]);
          *(bf16x4*)(A + row * AROWE + (k >> 3) * 8 + (k & 7)) = p;
          int kl = k + HALFK;
          *(bf16x4*)(A + row * AROWE + (kl >> 3) * 8 + (kl & 7)) = q;
        }
      }
    }
    __syncthreads();
  }
}

__global__ __launch_bounds__(512, 2) void lstm_main(const float* __restrict__ gh,
                                                    const float* __restrict__ ga,
                                                    const float* __restrict__ gv,
                                                    const float* __restrict__ ph,
                                                    const float* __restrict__ pa,
                                                    uint8_t* __restrict__ ws) {
  extern __shared__ uint8_t smem[];
  float* feat = (float*)(ws + OFF_FEAT);
  int bid = blockIdx.x;
  if (bid < 64) {
    lstm_tile3<16, 64, 256, 128, 8, 20, 10, 2, 6, 0>(
        gh, ga, 512, (const bf16*)(ws + OFF_W1), (const float*)(ws + OFF_B1), feat, bid, smem);
  } else if (bid < 96) {
    lstm_tile3<16, 64, 256, 128, 8, 20, 10, 2, 6, 1>(
        gv, gv, 512, (const bf16*)(ws + OFF_W2), (const float*)(ws + OFF_B2), feat, bid - 64, smem);
  } else {
    // design-3: BM=32, all W VGPR-resident (NS=0)
    lstm_tile3<32, 32, 128, 64, 4, 10, 5, 4, 0, 2>(
        ph, pa, 6144, (const bf16*)(ws + OFF_W3), (const float*)(ws + OFF_B3), feat, bid - 96, smem);
  }
}

// ---------------- final FC ----------------
__global__ void fc_kernel(const float* __restrict__ feat, const float* __restrict__ cg,
                          const float* __restrict__ Wfc, const float* __restrict__ bfc,
                          float* __restrict__ out) {
  int b = blockIdx.x, tid = threadIdx.x;
  float a0 = 0.f, a1 = 0.f;
  for (int c = tid; c < 3840; c += 256) {
    float f = feat[(size_t)b * 3840 + c];
    a0 += f * Wfc[c];
    a1 += f * Wfc[3872 + c];
  }
  if (tid < 32) {
    float f = cg[b * 32 + tid];
    a0 += f * Wfc[3840 + tid];
    a1 += f * Wfc[3872 + 3840 + tid];
  }
#pragma unroll
  for (int o = 32; o > 0; o >>= 1) {
    a0 += __shfl_down(a0, o);
    a1 += __shfl_down(a1, o);
  }
  __shared__ float red[8];
  int wv = tid >> 6;
  if ((tid & 63) == 0) { red[wv * 2] = a0; red[wv * 2 + 1] = a1; }
  __syncthreads();
  if (tid == 0) {
    out[b * 2 + 0] = red[0] + red[2] + red[4] + red[6] + bfc[0];
    out[b * 2 + 1] = red[1] + red[3] + red[5] + red[7] + bfc[1];
  }
}

extern "C" void kernel_launch(void* const* d_in, const int* in_sizes, int n_in, void* d_out,
                              int out_size, void* d_ws, size_t ws_size, hipStream_t stream) {
  const float* cg = (const float*)d_in[0];
  const float* gh = (const float*)d_in[1];
  const float* ga = (const float*)d_in[2];
  const float* gv = (const float*)d_in[3];
  const float* ph = (const float*)d_in[4];
  const float* pa = (const float*)d_in[5];
  const float* Wih1 = (const float*)d_in[6];
  const float* Whh1 = (const float*)d_in[7];
  const float* bih1 = (const float*)d_in[8];
  const float* bhh1 = (const float*)d_in[9];
  const float* Wih2 = (const float*)d_in[10];
  const float* Whh2 = (const float*)d_in[11];
  const float* bih2 = (const float*)d_in[12];
  const float* bhh2 = (const float*)d_in[13];
  const float* Wih3 = (const float*)d_in[14];
  const float* Whh3 = (const float*)d_in[15];
  const float* bih3 = (const float*)d_in[16];
  const float* bhh3 = (const float*)d_in[17];
  const float* Wfc = (const float*)d_in[18];
  const float* bfc = (const float*)d_in[19];
  uint8_t* ws = (uint8_t*)d_ws;
  if (ws_size < WS_NEEDED) return;

  hipLaunchKernelGGL(prep_kernel, dim3(512), dim3(256), 0, stream, Wih1, Whh1, bih1, bhh1,
                     Wih2, Whh2, bih2, bhh2, Wih3, Whh3, bih3, bhh3, ws);

  // LDS: A only. d1/d2: 16*(81*8)*2 = 20736 B; d3: 32*(41*8)*2 = 20992 B. <64KB default.
  hipLaunchKernelGGL(lstm_main, dim3(480), dim3(512), 20992, stream, gh, ga, gv, ph, pa, ws);

  hipLaunchKernelGGL(fc_kernel, dim3(512), dim3(256), 0, stream,
                     (const float*)(ws + OFF_FEAT), cg, Wfc, bfc, (float*)d_out);
}